// Round 4
// baseline (779.971 us; speedup 1.0000x reference)
//
#include <hip/hip_runtime.h>
#include <cstdint>
#include <math.h>

#define BATCH    65536
#define HIS_LEN  5
#define KIND_LEN 10

// ---- ws layout (fp32 element offsets) ----
#define OFF_WC1 0        // [64][176]  (wA+wB | wC-wB)
#define OFF_AB1 11264    // [64]
#define OFF_W2T 11328    // [64][32]   act_w2 transposed -> w2t[o*32+p]
#define OFF_AB2 13376    // [32]
#define OFF_W3  13408    // [32]
#define OFF_AB3 13440    // [1] (padded 16)
#define OFF_M1  13456    // [128][208]
#define OFF_MB1 40080    // [128]
#define OFF_M2T 40208    // [128][64]  mlp_w2 transposed -> m2t[o*64+p]
#define OFF_MB2 48400    // [64]
#define OFF_M3T 48464    // [64][32]   mlp_w3 transposed -> m3t[o*32+p]
#define OFF_MB3 50512    // [32]
#define OFF_M4  50544    // [32]
#define OFF_MB4 50576    // [1]
#define PREP_N  50562

__device__ __forceinline__ void load8(const float4* __restrict__ e, int idx, float* d){
  float4 a = e[idx*2];
  float4 b = e[idx*2+1];
  d[0]=a.x; d[1]=a.y; d[2]=a.z; d[3]=a.w;
  d[4]=b.x; d[5]=b.y; d[6]=b.z; d[7]=b.w;
}

__device__ __forceinline__ void gather_item_feat(const float4* __restrict__ item_emb,
                                                 const float4* __restrict__ kind_emb,
                                                 int item_idx,
                                                 const int* __restrict__ kidx,
                                                 float* f){
  load8(item_emb, item_idx, f);
  #pragma unroll
  for(int k=0;k<KIND_LEN;k++){
    int ki = kidx[k];
    float t[8]; load8(kind_emb, ki, t);
    #pragma unroll
    for(int j=0;j<8;j++) f[8+8*k+j] = ki ? t[j] : 0.0f;
  }
}

typedef const float* fp;

// ---- prep: combine/transpose all weights (fp32) into ws ----
__global__ void din_prep(fp aw1, fp ab1, fp aw2, fp ab2, fp aw3, fp ab3,
                         fp m1,  fp mb1, fp m2,  fp mb2, fp m3,  fp mb3,
                         fp m4,  fp mb4, float* __restrict__ ws){
  int i = blockIdx.x*blockDim.x + threadIdx.x;
  int j = i;
  if(j < 11264){
    int o = j/176, d = j%176;
    float v;
    if(d < 88) v = aw1[o*264 + d] + aw1[o*264 + 88 + d];
    else { int dd = d-88; v = aw1[o*264 + 176 + dd] - aw1[o*264 + 88 + dd]; }
    ws[OFF_WC1 + j] = v; return;
  } j -= 11264;
  if(j < 64){ ws[OFF_AB1 + j] = ab1[j]; return; } j -= 64;
  if(j < 2048){ int o=j/32, p=j%32; ws[OFF_W2T + j] = aw2[p*64 + o]; return; } j -= 2048;
  if(j < 32){ ws[OFF_AB2 + j] = ab2[j]; return; } j -= 32;
  if(j < 32){ ws[OFF_W3  + j] = aw3[j]; return; } j -= 32;
  if(j < 1){ ws[OFF_AB3] = ab3[0]; return; } j -= 1;
  if(j < 26624){ ws[OFF_M1 + j] = m1[j]; return; } j -= 26624;
  if(j < 128){ ws[OFF_MB1 + j] = mb1[j]; return; } j -= 128;
  if(j < 8192){ int o=j/64, p=j%64; ws[OFF_M2T + j] = m2[p*128 + o]; return; } j -= 8192;
  if(j < 64){ ws[OFF_MB2 + j] = mb2[j]; return; } j -= 64;
  if(j < 2048){ int o=j/32, p=j%32; ws[OFF_M3T + j] = m3[p*64 + o]; return; } j -= 2048;
  if(j < 32){ ws[OFF_MB3 + j] = mb3[j]; return; } j -= 32;
  if(j < 32){ ws[OFF_M4  + j] = m4[j];  return; } j -= 32;
  if(j < 1){ ws[OFF_MB4] = mb4[0]; return; }
}

// Block = 128 threads (2 waves) sharing the same 64 samples (lane = sample).
// Every o-dimension is split across the 2 waves; weights stay wave-uniform
// (s_load path); cross-wave partials combine via LDS.
// LDS regions (floats), phase-aliased:
//   act:   h2-exchange  [wave*2048 + p*64 + lane]   (0..4095)
//          t2           [4096 + wave*2048 + o*64 + lane]  (4096..8191)
//   after: pool         [d*64 + lane]               (0..5631)
//   mlp:   h2m-exchange (0..4095), h3-exchange (0..2047)
__global__ void __launch_bounds__(128, 2)
din_main(const int* __restrict__ userid, const int* __restrict__ itemid,
         const int* __restrict__ age,    const int* __restrict__ gen,
         const int* __restrict__ occ,    const int* __restrict__ item_kind,
         const int* __restrict__ his_id, const int* __restrict__ his_kind,
         const float4* __restrict__ user_emb, const float4* __restrict__ item_emb,
         const float4* __restrict__ age_emb,  const float4* __restrict__ gen_emb,
         const float4* __restrict__ occ_emb,  const float4* __restrict__ kind_emb,
         const float* __restrict__ ws, float* __restrict__ out){
  const int lane = threadIdx.x & 63;
  const int wave = __builtin_amdgcn_readfirstlane((int)(threadIdx.x >> 6));
  const int b = blockIdx.x*64 + lane;

  __shared__ float ls[8192];   // 32 KB

  // ---- phase A: t2[own 32 o's] = dot(wC-wB, i2) -> LDS ----
  {
    float i2r[88];
    gather_item_feat(item_emb, kind_emb, itemid[b], item_kind + b*KIND_LEN, i2r);
    #pragma unroll 2
    for(int o=0;o<32;o++){
      const float* __restrict__ w = ws + OFF_WC1 + (wave*32+o)*176 + 88;
      float a0=0.f,a1=0.f,a2=0.f,a3=0.f;
      #pragma unroll
      for(int d=0;d<88;d+=4){ a0+=w[d]*i2r[d]; a1+=w[d+1]*i2r[d+1]; a2+=w[d+2]*i2r[d+2]; a3+=w[d+3]*i2r[d+3]; }
      ls[4096 + wave*2048 + o*64 + lane] = (a0+a1)+(a2+a3);
    }
  }

  float pool_own[44];
  #pragma unroll
  for(int d=0;d<44;d++) pool_own[d]=0.f;

  // ---- history positions ----
  #pragma unroll 1
  for(int s=0;s<HIS_LEN;s++){
    float i1[88];
    gather_item_feat(item_emb, kind_emb, his_id[b*HIS_LEN+s], his_kind + (b*HIS_LEN+s)*KIND_LEN, i1);

    float h2p[32];
    #pragma unroll
    for(int p=0;p<32;p++) h2p[p] = (wave==0) ? ws[OFF_AB2+p] : 0.f;

    #pragma unroll 2
    for(int o=0;o<32;o++){
      const float* __restrict__ w = ws + OFF_WC1 + (wave*32+o)*176;
      float a0=0.f,a1=0.f,a2=0.f,a3=0.f;
      #pragma unroll
      for(int d=0;d<88;d+=4){ a0+=w[d]*i1[d]; a1+=w[d+1]*i1[d+1]; a2+=w[d+2]*i1[d+2]; a3+=w[d+3]*i1[d+3]; }
      float h = (a0+a1)+(a2+a3) + ls[4096 + wave*2048 + o*64 + lane] + ws[OFF_AB1 + wave*32 + o];
      h = fmaxf(h, 0.f);
      const float* __restrict__ w2 = ws + OFF_W2T + (wave*32+o)*32;
      #pragma unroll
      for(int p=0;p<32;p++) h2p[p] += w2[p]*h;
    }
    // exchange h2 partials
    #pragma unroll
    for(int p=0;p<32;p++) ls[wave*2048 + p*64 + lane] = h2p[p];
    __syncthreads();
    float sc = ws[OFF_AB3];
    {
      const int ow = (1-wave)*2048;
      #pragma unroll
      for(int p=0;p<32;p++){
        float hf = h2p[p] + ls[ow + p*64 + lane];
        sc += ws[OFF_W3+p]*fmaxf(hf,0.f);
      }
    }
    __syncthreads();   // reads done before next-iter overwrite / pool overwrite
    if(wave==0){
      #pragma unroll
      for(int d=0;d<44;d++){ float v=i1[d];    pool_own[d] += sc*v*v; }
    } else {
      #pragma unroll
      for(int d=0;d<44;d++){ float v=i1[44+d]; pool_own[d] += sc*v*v; }
    }
  }

  // ---- publish pool (full 88) to LDS ----
  if(wave==0){
    #pragma unroll
    for(int d=0;d<44;d++) ls[d*64+lane] = pool_own[d];
  } else {
    #pragma unroll
    for(int d=0;d<44;d++) ls[(44+d)*64+lane] = pool_own[d];
  }
  __syncthreads();

  // ---- main MLP layer 1+2 (own 64 o's of 128), o in blocks of 16, K chunked 104+104 ----
  float h2m[64];
  #pragma unroll
  for(int p=0;p<64;p++) h2m[p] = (wave==0)? ws[OFF_MB2+p] : 0.f;

  const int itk = b*KIND_LEN;
  #pragma unroll 1
  for(int og=0; og<4; og++){
    const int obase = wave*64 + og*16;
    float pa[16];
    #pragma unroll
    for(int i=0;i<16;i++) pa[i] = ws[OFF_MB1 + obase + i];
    { // chunk 0: feat[0:104] = uf, i2_item, af, gf, qf, kind rows 0..7
      float c[104];
      load8(user_emb, userid[b], c+0);
      load8(item_emb, itemid[b], c+8);
      load8(age_emb,  age[b],  c+16);
      load8(gen_emb,  gen[b],  c+24);
      load8(occ_emb,  occ[b],  c+32);
      #pragma unroll
      for(int k=0;k<8;k++){
        int ki = item_kind[itk+k];
        float t[8]; load8(kind_emb, ki, t);
        #pragma unroll
        for(int j=0;j<8;j++) c[40+8*k+j] = ki? t[j]:0.f;
      }
      #pragma unroll
      for(int i=0;i<16;i++){
        const float* __restrict__ w = ws + OFF_M1 + (obase+i)*208;
        float a0=0.f,a1=0.f,a2=0.f,a3=0.f;
        #pragma unroll
        for(int d=0;d<104;d+=4){ a0+=w[d]*c[d]; a1+=w[d+1]*c[d+1]; a2+=w[d+2]*c[d+2]; a3+=w[d+3]*c[d+3]; }
        pa[i] += (a0+a1)+(a2+a3);
      }
    }
    { // chunk 1: feat[104:208] = kind rows 8,9 + pool[0:88]
      float c[104];
      #pragma unroll
      for(int k=8;k<10;k++){
        int ki = item_kind[itk+k];
        float t[8]; load8(kind_emb, ki, t);
        #pragma unroll
        for(int j=0;j<8;j++) c[(k-8)*8+j] = ki? t[j]:0.f;
      }
      #pragma unroll
      for(int d=0;d<88;d++) c[16+d] = ls[d*64+lane];
      #pragma unroll
      for(int i=0;i<16;i++){
        const float* __restrict__ w = ws + OFF_M1 + (obase+i)*208 + 104;
        float a0=0.f,a1=0.f,a2=0.f,a3=0.f;
        #pragma unroll
        for(int d=0;d<104;d+=4){ a0+=w[d]*c[d]; a1+=w[d+1]*c[d+1]; a2+=w[d+2]*c[d+2]; a3+=w[d+3]*c[d+3]; }
        pa[i] += (a0+a1)+(a2+a3);
      }
    }
    #pragma unroll
    for(int i=0;i<16;i++){
      float h = fmaxf(pa[i], 0.f);
      const float* __restrict__ w2 = ws + OFF_M2T + (obase+i)*64;
      #pragma unroll
      for(int p=0;p<64;p++) h2m[p] += w2[p]*h;
    }
  }
  __syncthreads();   // all pool reads done before overwriting ls[0..4095]

  // ---- h2m exchange: each wave ends with its fully-reduced 32-neuron half ----
  if(wave==0){
    #pragma unroll
    for(int p=32;p<64;p++) ls[2048 + (p-32)*64 + lane] = h2m[p];
  } else {
    #pragma unroll
    for(int p=0;p<32;p++) ls[p*64 + lane] = h2m[p];
  }
  __syncthreads();

  float h3p[32];
  #pragma unroll
  for(int p=0;p<32;p++) h3p[p] = (wave==0)? ws[OFF_MB3+p] : 0.f;

  if(wave==0){
    #pragma unroll
    for(int o2=0;o2<32;o2++){
      float v = fmaxf(h2m[o2] + ls[o2*64+lane], 0.f);
      const float* __restrict__ w3 = ws + OFF_M3T + o2*32;
      #pragma unroll
      for(int p=0;p<32;p++) h3p[p] += w3[p]*v;
    }
  } else {
    #pragma unroll
    for(int o2=0;o2<32;o2++){
      float v = fmaxf(h2m[32+o2] + ls[2048 + o2*64+lane], 0.f);
      const float* __restrict__ w3 = ws + OFF_M3T + (32+o2)*32;
      #pragma unroll
      for(int p=0;p<32;p++) h3p[p] += w3[p]*v;
    }
  }
  __syncthreads();
  if(wave==1){
    #pragma unroll
    for(int p=0;p<32;p++) ls[p*64+lane] = h3p[p];
  }
  __syncthreads();
  if(wave==0){
    float x = ws[OFF_MB4];
    #pragma unroll
    for(int p=0;p<32;p++) x += ws[OFF_M4+p]*fmaxf(h3p[p] + ls[p*64+lane], 0.f);
    out[b] = 1.0f/(1.0f + __expf(-x));
  }
}

extern "C" void kernel_launch(void* const* d_in, const int* in_sizes, int n_in,
                              void* d_out, int out_size, void* d_ws, size_t ws_size,
                              hipStream_t stream){
  const int* userid    = (const int*)d_in[0];
  const int* itemid    = (const int*)d_in[1];
  const int* age       = (const int*)d_in[2];
  const int* gen       = (const int*)d_in[3];
  const int* occ       = (const int*)d_in[4];
  const int* item_kind = (const int*)d_in[5];
  const int* his_id    = (const int*)d_in[6];
  const int* his_kind  = (const int*)d_in[7];
  const float4* user_emb = (const float4*)d_in[8];
  const float4* item_emb = (const float4*)d_in[9];
  const float4* age_emb  = (const float4*)d_in[10];
  const float4* gen_emb  = (const float4*)d_in[11];
  const float4* occ_emb  = (const float4*)d_in[12];
  const float4* kind_emb = (const float4*)d_in[13];
  float* ws = (float*)d_ws;

  din_prep<<<(PREP_N+255)/256, 256, 0, stream>>>(
      (fp)d_in[14], (fp)d_in[15], (fp)d_in[16], (fp)d_in[17], (fp)d_in[18], (fp)d_in[19],
      (fp)d_in[20], (fp)d_in[21], (fp)d_in[22], (fp)d_in[23], (fp)d_in[24], (fp)d_in[25],
      (fp)d_in[26], (fp)d_in[27], ws);

  din_main<<<BATCH/64, 128, 0, stream>>>(
      userid, itemid, age, gen, occ, item_kind, his_id, his_kind,
      user_emb, item_emb, age_emb, gen_emb, occ_emb, kind_emb,
      ws, (float*)d_out);
}